// Round 3
// baseline (955.917 us; speedup 1.0000x reference)
//
#include <hip/hip_runtime.h>
#include <hip/hip_bf16.h>

typedef __attribute__((ext_vector_type(8))) short bf16x8;
typedef __attribute__((ext_vector_type(4))) float f32x4;
typedef __hip_bfloat16 bf16;

#define S_LEN 2048
#define HIDDEN 4096
#define NH 32
#define NKV 8
#define DH 128
#define ROTD 64
#define QKVW 6144              // fused QKV row width (32*128 + 8*128 + 8*128)
#define KOFF 4096              // K column offset in fused buffer
#define VOFF 5120              // V column offset
#define ATT_SCALE 0.08838834764831845f
#define RMS_EPS 1e-6f
#define PSTRIDE 68             // padded P-buffer row stride (64 would 4-way bank-conflict)

static __device__ __forceinline__ unsigned short f2bu(float f) {
    bf16 h = __float2bfloat16(f);
    return __builtin_bit_cast(unsigned short, h);
}

static __device__ __forceinline__ void load_lds_16(const bf16* g, bf16* l) {
    __builtin_amdgcn_global_load_lds((const __attribute__((address_space(1))) void*)g,
                                     (__attribute__((address_space(3))) void*)l, 16, 0, 0);
}

// ---------------- fp32 -> bf16 cast (vectorized float4) ----------------
__global__ __launch_bounds__(256) void cast_f32_bf16(const float* __restrict__ src,
                                                     unsigned short* __restrict__ dst, int n4) {
    int i = blockIdx.x * 256 + threadIdx.x;
    if (i >= n4) return;
    float4 v = reinterpret_cast<const float4*>(src)[i];
    ushort4 o;
    o.x = f2bu(v.x); o.y = f2bu(v.y); o.z = f2bu(v.z); o.w = f2bu(v.w);
    reinterpret_cast<ushort4*>(dst)[i] = o;
}

// ---------------- C[M,N] = A[M,K] @ B[N,K]^T, m97-style LDS-staged ----------------
// 128x128 block tile, BK=32, 256 threads. Wave w computes 64x64 (4x4 of 16x16 MFMA).
template <typename OutT>
__global__ __launch_bounds__(256) void gemm_lds(const bf16* __restrict__ A,
                                                const bf16* __restrict__ B,
                                                OutT* __restrict__ C,
                                                int M, int N, int K) {
    __shared__ bf16 As[128 * 32];
    __shared__ bf16 Bs[128 * 32];
    const int tid  = threadIdx.x;
    const int lane = tid & 63;
    const int wave = tid >> 6;
    const int lq   = lane & 15;
    const int quad = lane >> 4;
    const int m0 = blockIdx.y * 128;
    const int n0 = blockIdx.x * 128;
    const int wm = (wave & 1) * 64;
    const int wn = (wave >> 1) * 64;

    f32x4 acc[4][4] = {};

    const int ar = tid >> 2;
    const int ac = (tid & 3) * 8;
    const bf16* Ag0 = A + (size_t)(m0 + ar) * K + ac;
    const bf16* Ag1 = Ag0 + (size_t)64 * K;
    const bf16* Bg0 = B + (size_t)(n0 + ar) * K + ac;
    const bf16* Bg1 = Bg0 + (size_t)64 * K;
    bf16* Asl0 = As + wave * 512;
    bf16* Asl1 = As + wave * 512 + 2048;
    bf16* Bsl0 = Bs + wave * 512;
    bf16* Bsl1 = Bs + wave * 512 + 2048;

    for (int k0 = 0; k0 < K; k0 += 32) {
        load_lds_16(Ag0 + k0, Asl0);
        load_lds_16(Ag1 + k0, Asl1);
        load_lds_16(Bg0 + k0, Bsl0);
        load_lds_16(Bg1 + k0, Bsl1);
        __syncthreads();
        bf16x8 av[4], bv[4];
#pragma unroll
        for (int i = 0; i < 4; ++i)
            av[i] = *reinterpret_cast<const bf16x8*>(As + (wm + i * 16 + lq) * 32 + quad * 8);
#pragma unroll
        for (int i = 0; i < 4; ++i)
            bv[i] = *reinterpret_cast<const bf16x8*>(Bs + (wn + i * 16 + lq) * 32 + quad * 8);
#pragma unroll
        for (int mt = 0; mt < 4; ++mt)
#pragma unroll
            for (int nt = 0; nt < 4; ++nt)
                acc[mt][nt] = __builtin_amdgcn_mfma_f32_16x16x32_bf16(av[mt], bv[nt], acc[mt][nt], 0, 0, 0);
        __syncthreads();
    }

#pragma unroll
    for (int mt = 0; mt < 4; ++mt)
#pragma unroll
        for (int nt = 0; nt < 4; ++nt)
#pragma unroll
            for (int r = 0; r < 4; ++r) {
                float v = acc[mt][nt][r];
                size_t idx = (size_t)(m0 + wm + mt * 16 + quad * 4 + r) * N + n0 + wn + nt * 16 + lq;
                if constexpr (sizeof(OutT) == 2) C[idx] = __float2bfloat16(v);
                else                             C[idx] = v;
            }
}

// ---------------- fused RMSNorm + partial RoPE (in place, strided) ----------------
__global__ __launch_bounds__(256) void norm_rope(bf16* __restrict__ buf,
                                                 const float* __restrict__ w,
                                                 const float* __restrict__ cosp,
                                                 const float* __restrict__ sinp,
                                                 int log2nh, int stride, int coloff) {
    const int lane = threadIdx.x & 63;
    const int wave = threadIdx.x >> 6;
    const int row  = blockIdx.x * 4 + wave;
    const int s    = row >> log2nh;
    const int hh   = row & ((1 << log2nh) - 1);
    bf16* p = buf + (size_t)s * stride + coloff + hh * DH;

    float x1 = __bfloat162float(p[lane]);
    float x2 = __bfloat162float(p[64 + lane]);

    float ss = x1 * x1 + x2 * x2;
#pragma unroll
    for (int off = 1; off < 64; off <<= 1) ss += __shfl_xor(ss, off);
    float rs = rsqrtf(ss * (1.0f / 128.0f) + RMS_EPS);

    float y1 = x1 * rs * w[lane];
    float y2 = x2 * rs * w[64 + lane];

    float partner = __shfl_xor(y1, 32);
    float c  = cosp[(size_t)s * ROTD + lane];
    float sn = sinp[(size_t)s * ROTD + lane];
    float rot = (lane < 32) ? (y1 * c - partner * sn) : (y1 * c + partner * sn);

    p[lane]      = __float2bfloat16(rot);
    p[64 + lane] = __float2bfloat16(y2);
}

// ---------------- V transpose: qkv V cols -> vt(NKV*DH, S) ----------------
__global__ __launch_bounds__(256) void transpose_v(const bf16* __restrict__ v,
                                                   bf16* __restrict__ vt,
                                                   int stride, int colofs) {
    __shared__ bf16 t[32][65];
    const int c0 = blockIdx.x * 32;
    const int s0 = blockIdx.y * 64;
    {
        const int j  = threadIdx.x & 31;
        const int i0 = threadIdx.x >> 5;
#pragma unroll
        for (int p = 0; p < 8; ++p) {
            int si = p * 8 + i0;
            t[j][si] = v[(size_t)(s0 + si) * stride + colofs + c0 + j];
        }
    }
    __syncthreads();
    {
        const int ii = threadIdx.x & 63;
        const int j0 = threadIdx.x >> 6;
#pragma unroll
        for (int p = 0; p < 8; ++p) {
            int c = p * 4 + j0;
            vt[(size_t)(c0 + c) * S_LEN + s0 + ii] = t[c][ii];
        }
    }
}

// ---------------- MFMA flash attention (causal, GQA) ----------------
// One wave per (head, 16-row q-tile): 4096 waves / 1024 blocks, heavy tiles first.
__global__ __launch_bounds__(256) void flash_attn(const bf16* __restrict__ QKV,
                                                  const bf16* __restrict__ VT,
                                                  bf16* __restrict__ O) {
    __shared__ bf16 pbuf[4][16 * PSTRIDE];
    const int lane = threadIdx.x & 63;
    const int wave = threadIdx.x >> 6;
    const int lq   = lane & 15;
    const int quad = lane >> 4;
    const int w    = blockIdx.x * 4 + wave;   // 0..4095
    const int h    = w >> 7;                  // 0..31
    const int qt   = 127 - (w & 127);         // heavy tiles first
    const int q0   = qt * 16;
    const int kvh  = h >> 2;                  // GQA rep=4
    bf16* pb = pbuf[wave];

    // Q fragments, A-layout, with softmax scale folded in
    bf16x8 qf[4];
    const bf16* qrow = QKV + (size_t)(q0 + lq) * QKVW + h * DH + quad * 8;
#pragma unroll
    for (int i = 0; i < 4; ++i) {
        bf16x8 qv = *reinterpret_cast<const bf16x8*>(qrow + 32 * i);
#pragma unroll
        for (int j = 0; j < 8; ++j) {
            bf16 b = __builtin_bit_cast(bf16, (unsigned short)qv[j]);
            qv[j] = (short)__builtin_bit_cast(unsigned short,
                        __float2bfloat16(__bfloat162float(b) * ATT_SCALE));
        }
        qf[i] = qv;
    }

    f32x4 o[8];
#pragma unroll
    for (int t2 = 0; t2 < 8; ++t2) o[t2] = (f32x4){0.f, 0.f, 0.f, 0.f};
    float m_i[4], l_i[4];
#pragma unroll
    for (int r = 0; r < 4; ++r) { m_i[r] = -1e30f; l_i[r] = 0.f; }

    const int limit = q0 + 16;
    for (int k0 = 0; k0 < limit; k0 += 64) {
        int nt = (limit - k0) >> 4; if (nt > 4) nt = 4;
        float p[4][4];
#pragma unroll
        for (int t = 0; t < 4; ++t) {
            if (t < nt) {
                f32x4 sacc = (f32x4){0.f, 0.f, 0.f, 0.f};
                const int kc = k0 + 16 * t;
                const bf16* kp = QKV + (size_t)(kc + lq) * QKVW + KOFF + kvh * DH + quad * 8;
#pragma unroll
                for (int i = 0; i < 4; ++i) {
                    bf16x8 kf = *reinterpret_cast<const bf16x8*>(kp + 32 * i);
                    sacc = __builtin_amdgcn_mfma_f32_16x16x32_bf16(qf[i], kf, sacc, 0, 0, 0);
                }
#pragma unroll
                for (int r = 0; r < 4; ++r) {
                    int qi = q0 + quad * 4 + r;
                    int ki = kc + lq;
                    p[t][r] = (ki > qi) ? -1e30f : sacc[r];
                }
            } else {
#pragma unroll
                for (int r = 0; r < 4; ++r) p[t][r] = -1e30f;
            }
        }
        float rowmax[4];
#pragma unroll
        for (int r = 0; r < 4; ++r)
            rowmax[r] = fmaxf(fmaxf(p[0][r], p[1][r]), fmaxf(p[2][r], p[3][r]));
#pragma unroll
        for (int off = 1; off < 16; off <<= 1)
#pragma unroll
            for (int r = 0; r < 4; ++r) rowmax[r] = fmaxf(rowmax[r], __shfl_xor(rowmax[r], off));

        float alpha[4];
#pragma unroll
        for (int r = 0; r < 4; ++r) {
            float mn = fmaxf(m_i[r], rowmax[r]);
            alpha[r] = __expf(m_i[r] - mn);
            m_i[r] = mn;
        }
#pragma unroll
        for (int t = 0; t < 4; ++t) {
            if (t < nt) {
#pragma unroll
                for (int r = 0; r < 4; ++r) p[t][r] = __expf(p[t][r] - m_i[r]);
            } else {
#pragma unroll
                for (int r = 0; r < 4; ++r) p[t][r] = 0.f;
            }
        }

        float rsum[4];
#pragma unroll
        for (int r = 0; r < 4; ++r) rsum[r] = (p[0][r] + p[1][r]) + (p[2][r] + p[3][r]);
#pragma unroll
        for (int off = 1; off < 16; off <<= 1)
#pragma unroll
            for (int r = 0; r < 4; ++r) rsum[r] += __shfl_xor(rsum[r], off);
#pragma unroll
        for (int r = 0; r < 4; ++r) l_i[r] = l_i[r] * alpha[r] + rsum[r];

        // P (C-layout) -> LDS (padded rows) -> A-layout fragments
#pragma unroll
        for (int t = 0; t < 4; ++t)
#pragma unroll
            for (int r = 0; r < 4; ++r)
                pb[(quad * 4 + r) * PSTRIDE + t * 16 + lq] = __float2bfloat16(p[t][r]);
        __threadfence_block();

#pragma unroll
        for (int t2 = 0; t2 < 8; ++t2)
#pragma unroll
            for (int r = 0; r < 4; ++r) o[t2][r] *= alpha[r];

        const int nh2 = (nt + 1) >> 1;
        for (int hh = 0; hh < nh2; ++hh) {
            bf16x8 pa = *reinterpret_cast<const bf16x8*>(pb + lq * PSTRIDE + hh * 32 + quad * 8);
            const bf16* vp = VT + (size_t)(kvh * DH + lq) * S_LEN + k0 + hh * 32 + quad * 8;
#pragma unroll
            for (int t2 = 0; t2 < 8; ++t2) {
                bf16x8 vf = *reinterpret_cast<const bf16x8*>(vp + (size_t)t2 * 16 * S_LEN);
                o[t2] = __builtin_amdgcn_mfma_f32_16x16x32_bf16(pa, vf, o[t2], 0, 0, 0);
            }
        }
        __threadfence_block();
    }

#pragma unroll
    for (int r = 0; r < 4; ++r) l_i[r] = 1.0f / l_i[r];
#pragma unroll
    for (int t2 = 0; t2 < 8; ++t2)
#pragma unroll
        for (int r = 0; r < 4; ++r)
            O[(size_t)(q0 + quad * 4 + r) * (NH * DH) + h * DH + t2 * 16 + lq] =
                __float2bfloat16(o[t2][r] * l_i[r]);
}

extern "C" void kernel_launch(void* const* d_in, const int* in_sizes, int n_in,
                              void* d_out, int out_size, void* d_ws, size_t ws_size,
                              hipStream_t stream) {
    const float* hs   = (const float*)d_in[0];
    const float* cosp = (const float*)d_in[1];
    const float* sinp = (const float*)d_in[2];
    const float* Wq   = (const float*)d_in[3];
    const float* Wk   = (const float*)d_in[4];
    const float* Wv   = (const float*)d_in[5];
    const float* Wo   = (const float*)d_in[6];
    const float* qw   = (const float*)d_in[7];
    const float* kw   = (const float*)d_in[8];
    float* out = (float*)d_out;

    char* ws = (char*)d_ws;
    size_t off = 0;
    auto carve = [&](size_t bytes) { char* p = ws + off; off += (bytes + 255) & ~(size_t)255; return p; };

    bf16* hsb  = (bf16*)carve((size_t)S_LEN * HIDDEN * 2);          // hidden bf16; reused as AO
    bf16* wqkv = (bf16*)carve((size_t)QKVW * HIDDEN * 2);           // fused [6144, 4096]
    bf16* wob  = (bf16*)carve((size_t)HIDDEN * NH * DH * 2);
    bf16* qkv  = (bf16*)carve((size_t)S_LEN * QKVW * 2);            // [S, 6144]
    bf16* vtb  = (bf16*)carve((size_t)NKV * DH * S_LEN * 2);

    // 1. casts
    cast_f32_bf16<<<(S_LEN * HIDDEN / 4 + 255) / 256, 256, 0, stream>>>(hs, (unsigned short*)hsb, S_LEN * HIDDEN / 4);
    cast_f32_bf16<<<(NH * DH * HIDDEN / 4 + 255) / 256, 256, 0, stream>>>(Wq, (unsigned short*)wqkv, NH * DH * HIDDEN / 4);
    cast_f32_bf16<<<(NKV * DH * HIDDEN / 4 + 255) / 256, 256, 0, stream>>>(Wk, (unsigned short*)(wqkv + (size_t)KOFF * HIDDEN), NKV * DH * HIDDEN / 4);
    cast_f32_bf16<<<(NKV * DH * HIDDEN / 4 + 255) / 256, 256, 0, stream>>>(Wv, (unsigned short*)(wqkv + (size_t)VOFF * HIDDEN), NKV * DH * HIDDEN / 4);
    cast_f32_bf16<<<(HIDDEN * NH * DH / 4 + 255) / 256, 256, 0, stream>>>(Wo, (unsigned short*)wob, HIDDEN * NH * DH / 4);

    // 2. fused QKV projection
    gemm_lds<bf16><<<dim3(QKVW / 128, S_LEN / 128), 256, 0, stream>>>(hsb, wqkv, qkv, S_LEN, QKVW, HIDDEN);

    // 3. rmsnorm + rope in place on Q and K slices
    norm_rope<<<S_LEN * NH / 4, 256, 0, stream>>>(qkv, qw, cosp, sinp, 5, QKVW, 0);
    norm_rope<<<S_LEN * NKV / 4, 256, 0, stream>>>(qkv, kw, cosp, sinp, 3, QKVW, KOFF);

    // 4. V transpose
    transpose_v<<<dim3(NKV * DH / 32, S_LEN / 64), 256, 0, stream>>>(qkv, vtb, QKVW, VOFF);

    // 5. flash attention -> AO (reuse hsb)
    bf16* aob = hsb;
    flash_attn<<<NH * 128 / 4, 256, 0, stream>>>(qkv, vtb, aob);

    // 6. output projection (fp32 out)
    gemm_lds<float><<<dim3(HIDDEN / 128, S_LEN / 128), 256, 0, stream>>>(aob, wob, out, S_LEN, HIDDEN, NH * DH);
}

// Round 4
// 576.415 us; speedup vs baseline: 1.6584x; 1.6584x over previous
//
#include <hip/hip_runtime.h>
#include <hip/hip_bf16.h>

typedef __attribute__((ext_vector_type(8))) short bf16x8;
typedef __attribute__((ext_vector_type(4))) float f32x4;
typedef __hip_bfloat16 bf16;

#define S_LEN 2048
#define HIDDEN 4096
#define NH 32
#define NKV 8
#define DH 128
#define ROTD 64
#define QKVW 6144              // fused QKV row width (32*128 + 8*128 + 8*128)
#define KOFF 4096              // K column offset in fused buffer
#define VOFF 5120              // V column offset
#define ATT_SCALE 0.08838834764831845f
#define RMS_EPS 1e-6f
#define KPITCH 136             // Ks row pitch (elems): 272B = 17*16 -> aligned, 2-way banks
#define VPITCH 72              // Vs/Ps row pitch: 144B = 9*16 -> aligned, 2-way banks

static __device__ __forceinline__ unsigned short f2bu(float f) {
    bf16 h = __float2bfloat16(f);
    return __builtin_bit_cast(unsigned short, h);
}

static __device__ __forceinline__ void load_lds_16(const bf16* g, bf16* l) {
    __builtin_amdgcn_global_load_lds((const __attribute__((address_space(1))) void*)g,
                                     (__attribute__((address_space(3))) void*)l, 16, 0, 0);
}

// ---------------- fp32 -> bf16 cast (vectorized float4) ----------------
__global__ __launch_bounds__(256) void cast_f32_bf16(const float* __restrict__ src,
                                                     unsigned short* __restrict__ dst, int n4) {
    int i = blockIdx.x * 256 + threadIdx.x;
    if (i >= n4) return;
    float4 v = reinterpret_cast<const float4*>(src)[i];
    ushort4 o;
    o.x = f2bu(v.x); o.y = f2bu(v.y); o.z = f2bu(v.z); o.w = f2bu(v.w);
    reinterpret_cast<ushort4*>(dst)[i] = o;
}

// ---------------- C[M,N] = A[M,K] @ B[N,K]^T, m97-style LDS-staged ----------------
template <typename OutT>
__global__ __launch_bounds__(256) void gemm_lds(const bf16* __restrict__ A,
                                                const bf16* __restrict__ B,
                                                OutT* __restrict__ C,
                                                int M, int N, int K) {
    __shared__ bf16 As[128 * 32];
    __shared__ bf16 Bs[128 * 32];
    const int tid  = threadIdx.x;
    const int lane = tid & 63;
    const int wave = tid >> 6;
    const int lq   = lane & 15;
    const int quad = lane >> 4;
    const int m0 = blockIdx.y * 128;
    const int n0 = blockIdx.x * 128;
    const int wm = (wave & 1) * 64;
    const int wn = (wave >> 1) * 64;

    f32x4 acc[4][4] = {};

    const int ar = tid >> 2;
    const int ac = (tid & 3) * 8;
    const bf16* Ag0 = A + (size_t)(m0 + ar) * K + ac;
    const bf16* Ag1 = Ag0 + (size_t)64 * K;
    const bf16* Bg0 = B + (size_t)(n0 + ar) * K + ac;
    const bf16* Bg1 = Bg0 + (size_t)64 * K;
    bf16* Asl0 = As + wave * 512;
    bf16* Asl1 = As + wave * 512 + 2048;
    bf16* Bsl0 = Bs + wave * 512;
    bf16* Bsl1 = Bs + wave * 512 + 2048;

    for (int k0 = 0; k0 < K; k0 += 32) {
        load_lds_16(Ag0 + k0, Asl0);
        load_lds_16(Ag1 + k0, Asl1);
        load_lds_16(Bg0 + k0, Bsl0);
        load_lds_16(Bg1 + k0, Bsl1);
        __syncthreads();
        bf16x8 av[4], bv[4];
#pragma unroll
        for (int i = 0; i < 4; ++i)
            av[i] = *reinterpret_cast<const bf16x8*>(As + (wm + i * 16 + lq) * 32 + quad * 8);
#pragma unroll
        for (int i = 0; i < 4; ++i)
            bv[i] = *reinterpret_cast<const bf16x8*>(Bs + (wn + i * 16 + lq) * 32 + quad * 8);
#pragma unroll
        for (int mt = 0; mt < 4; ++mt)
#pragma unroll
            for (int nt = 0; nt < 4; ++nt)
                acc[mt][nt] = __builtin_amdgcn_mfma_f32_16x16x32_bf16(av[mt], bv[nt], acc[mt][nt], 0, 0, 0);
        __syncthreads();
    }

#pragma unroll
    for (int mt = 0; mt < 4; ++mt)
#pragma unroll
        for (int nt = 0; nt < 4; ++nt)
#pragma unroll
            for (int r = 0; r < 4; ++r) {
                float v = acc[mt][nt][r];
                size_t idx = (size_t)(m0 + wm + mt * 16 + quad * 4 + r) * N + n0 + wn + nt * 16 + lq;
                if constexpr (sizeof(OutT) == 2) C[idx] = __float2bfloat16(v);
                else                             C[idx] = v;
            }
}

// ---------------- fused RMSNorm + partial RoPE (in place, strided) ----------------
__global__ __launch_bounds__(256) void norm_rope(bf16* __restrict__ buf,
                                                 const float* __restrict__ w,
                                                 const float* __restrict__ cosp,
                                                 const float* __restrict__ sinp,
                                                 int log2nh, int stride, int coloff) {
    const int lane = threadIdx.x & 63;
    const int wave = threadIdx.x >> 6;
    const int row  = blockIdx.x * 4 + wave;
    const int s    = row >> log2nh;
    const int hh   = row & ((1 << log2nh) - 1);
    bf16* p = buf + (size_t)s * stride + coloff + hh * DH;

    float x1 = __bfloat162float(p[lane]);
    float x2 = __bfloat162float(p[64 + lane]);

    float ss = x1 * x1 + x2 * x2;
#pragma unroll
    for (int off = 1; off < 64; off <<= 1) ss += __shfl_xor(ss, off);
    float rs = rsqrtf(ss * (1.0f / 128.0f) + RMS_EPS);

    float y1 = x1 * rs * w[lane];
    float y2 = x2 * rs * w[64 + lane];

    float partner = __shfl_xor(y1, 32);
    float c  = cosp[(size_t)s * ROTD + lane];
    float sn = sinp[(size_t)s * ROTD + lane];
    float rot = (lane < 32) ? (y1 * c - partner * sn) : (y1 * c + partner * sn);

    p[lane]      = __float2bfloat16(rot);
    p[64 + lane] = __float2bfloat16(y2);
}

// ---------------- V transpose: qkv V cols -> vt(NKV*DH, S) ----------------
__global__ __launch_bounds__(256) void transpose_v(const bf16* __restrict__ v,
                                                   bf16* __restrict__ vt,
                                                   int stride, int colofs) {
    __shared__ bf16 t[32][65];
    const int c0 = blockIdx.x * 32;
    const int s0 = blockIdx.y * 64;
    {
        const int j  = threadIdx.x & 31;
        const int i0 = threadIdx.x >> 5;
#pragma unroll
        for (int p = 0; p < 8; ++p) {
            int si = p * 8 + i0;
            t[j][si] = v[(size_t)(s0 + si) * stride + colofs + c0 + j];
        }
    }
    __syncthreads();
    {
        const int ii = threadIdx.x & 63;
        const int j0 = threadIdx.x >> 6;
#pragma unroll
        for (int p = 0; p < 8; ++p) {
            int c = p * 4 + j0;
            vt[(size_t)(c0 + c) * S_LEN + s0 + ii] = t[c][ii];
        }
    }
}

// ---------------- block-cooperative MFMA flash attention (causal, GQA) ----------------
// Block = 4 waves, one head, 64 q-rows per call. K/V tiles (64 keys) staged in LDS via
// register-prefetch pipeline. Paired q-blocks (pr, 31-pr) -> uniform 33 iterations/block.
struct FlashSmem {
    bf16 Ks[64][KPITCH];    // keys x dh
    bf16 Vs[128][VPITCH];   // dh x keys
    bf16 Ps[4][16][VPITCH]; // per-wave P round-trip
};

static __device__ __forceinline__ void attn_qblock(int q0, int n_iter, int h, int kvh,
                                                   const bf16* __restrict__ QKV,
                                                   const bf16* __restrict__ VT,
                                                   bf16* __restrict__ O,
                                                   FlashSmem* sm) {
    const int tid  = threadIdx.x;
    const int lane = tid & 63;
    const int wave = tid >> 6;
    const int lq   = lane & 15;
    const int quad = lane >> 4;
    const int qr0  = q0 + wave * 16;

    // Q fragments (A-layout), softmax scale folded
    bf16x8 qf[4];
    const bf16* qrow = QKV + (size_t)(qr0 + lq) * QKVW + h * DH + quad * 8;
#pragma unroll
    for (int i = 0; i < 4; ++i) {
        bf16x8 qv = *reinterpret_cast<const bf16x8*>(qrow + 32 * i);
#pragma unroll
        for (int j = 0; j < 8; ++j) {
            bf16 b = __builtin_bit_cast(bf16, (unsigned short)qv[j]);
            qv[j] = (short)__builtin_bit_cast(unsigned short,
                        __float2bfloat16(__bfloat162float(b) * ATT_SCALE));
        }
        qf[i] = qv;
    }

    f32x4 o[8];
#pragma unroll
    for (int t2 = 0; t2 < 8; ++t2) o[t2] = (f32x4){0.f, 0.f, 0.f, 0.f};
    float m_i[4], l_i[4];
#pragma unroll
    for (int r = 0; r < 4; ++r) { m_i[r] = -1e30f; l_i[r] = 0.f; }

    // staging addresses: K thread t -> key row t>>2, 64B chunk t&3
    //                    V thread t -> dh row  t>>1, 64B chunk t&1
    const bf16* kg = QKV + (size_t)(tid >> 2) * QKVW + KOFF + kvh * DH + (tid & 3) * 32;
    const bf16* vg = VT + (size_t)(kvh * DH + (tid >> 1)) * S_LEN + (tid & 1) * 32;
    bf16* ksl = &sm->Ks[tid >> 2][(tid & 3) * 32];
    bf16* vsl = &sm->Vs[tid >> 1][(tid & 1) * 32];
    bf16* pb  = &sm->Ps[wave][0][0];

    bf16x8 kreg[4], vreg[4];
#pragma unroll
    for (int c = 0; c < 4; ++c) {
        kreg[c] = *reinterpret_cast<const bf16x8*>(kg + 8 * c);
        vreg[c] = *reinterpret_cast<const bf16x8*>(vg + 8 * c);
    }

    for (int kt = 0; kt < n_iter; ++kt) {
        const int k0 = kt * 64;
#pragma unroll
        for (int c = 0; c < 4; ++c) {
            *reinterpret_cast<bf16x8*>(ksl + 8 * c) = kreg[c];
            *reinterpret_cast<bf16x8*>(vsl + 8 * c) = vreg[c];
        }
        __syncthreads();
        if (kt + 1 < n_iter) {
            const size_t kadv = (size_t)(kt + 1) * 64;
#pragma unroll
            for (int c = 0; c < 4; ++c) {
                kreg[c] = *reinterpret_cast<const bf16x8*>(kg + kadv * QKVW + 8 * c);
                vreg[c] = *reinterpret_cast<const bf16x8*>(vg + kadv + 8 * c);
            }
        }

        // QK^T on the staged tile
        float p[4][4];
#pragma unroll
        for (int t = 0; t < 4; ++t) {
            f32x4 sacc = (f32x4){0.f, 0.f, 0.f, 0.f};
#pragma unroll
            for (int i = 0; i < 4; ++i) {
                bf16x8 kf = *reinterpret_cast<const bf16x8*>(&sm->Ks[t * 16 + lq][quad * 8 + 32 * i]);
                sacc = __builtin_amdgcn_mfma_f32_16x16x32_bf16(qf[i], kf, sacc, 0, 0, 0);
            }
#pragma unroll
            for (int r = 0; r < 4; ++r) {
                int qi = qr0 + quad * 4 + r;
                int ki = k0 + t * 16 + lq;
                p[t][r] = (ki > qi) ? -1e30f : sacc[r];
            }
        }

        float rowmax[4];
#pragma unroll
        for (int r = 0; r < 4; ++r)
            rowmax[r] = fmaxf(fmaxf(p[0][r], p[1][r]), fmaxf(p[2][r], p[3][r]));
#pragma unroll
        for (int off = 1; off < 16; off <<= 1)
#pragma unroll
            for (int r = 0; r < 4; ++r) rowmax[r] = fmaxf(rowmax[r], __shfl_xor(rowmax[r], off));

        float alpha[4];
#pragma unroll
        for (int r = 0; r < 4; ++r) {
            float mn = fmaxf(m_i[r], rowmax[r]);
            alpha[r] = __expf(m_i[r] - mn);
            m_i[r] = mn;
        }
#pragma unroll
        for (int t = 0; t < 4; ++t)
#pragma unroll
            for (int r = 0; r < 4; ++r) p[t][r] = __expf(p[t][r] - m_i[r]);

        float rsum[4];
#pragma unroll
        for (int r = 0; r < 4; ++r) rsum[r] = (p[0][r] + p[1][r]) + (p[2][r] + p[3][r]);
#pragma unroll
        for (int off = 1; off < 16; off <<= 1)
#pragma unroll
            for (int r = 0; r < 4; ++r) rsum[r] += __shfl_xor(rsum[r], off);
#pragma unroll
        for (int r = 0; r < 4; ++r) l_i[r] = l_i[r] * alpha[r] + rsum[r];

        // P (C-layout) -> per-wave LDS -> A-layout
#pragma unroll
        for (int t = 0; t < 4; ++t)
#pragma unroll
            for (int r = 0; r < 4; ++r)
                pb[(quad * 4 + r) * VPITCH + t * 16 + lq] = __float2bfloat16(p[t][r]);
        __threadfence_block();

#pragma unroll
        for (int t2 = 0; t2 < 8; ++t2)
#pragma unroll
            for (int r = 0; r < 4; ++r) o[t2][r] *= alpha[r];

#pragma unroll
        for (int hh = 0; hh < 2; ++hh) {
            bf16x8 pa = *reinterpret_cast<const bf16x8*>(pb + lq * VPITCH + hh * 32 + quad * 8);
#pragma unroll
            for (int t2 = 0; t2 < 8; ++t2) {
                bf16x8 vf = *reinterpret_cast<const bf16x8*>(&sm->Vs[t2 * 16 + lq][hh * 32 + quad * 8]);
                o[t2] = __builtin_amdgcn_mfma_f32_16x16x32_bf16(pa, vf, o[t2], 0, 0, 0);
            }
        }
        __syncthreads();   // protect Ks/Vs (and Ps) before next staging store
    }

#pragma unroll
    for (int r = 0; r < 4; ++r) l_i[r] = 1.0f / l_i[r];
#pragma unroll
    for (int t2 = 0; t2 < 8; ++t2)
#pragma unroll
        for (int r = 0; r < 4; ++r)
            O[(size_t)(qr0 + quad * 4 + r) * (NH * DH) + h * DH + t2 * 16 + lq] =
                __float2bfloat16(o[t2][r] * l_i[r]);
}

__global__ __launch_bounds__(256) void flash_attn(const bf16* __restrict__ QKV,
                                                  const bf16* __restrict__ VT,
                                                  bf16* __restrict__ O) {
    __shared__ FlashSmem sm;
    const int b  = blockIdx.x;       // 0..511
    const int h  = b & 31;
    const int pr = b >> 5;           // 0..15
    const int kvh = h >> 2;
    // heavy q-block first, then its light complement: uniform 33 iterations total
    attn_qblock((31 - pr) * 64, 32 - pr, h, kvh, QKV, VT, O, &sm);
    __syncthreads();
    attn_qblock(pr * 64,        pr + 1,  h, kvh, QKV, VT, O, &sm);
}

extern "C" void kernel_launch(void* const* d_in, const int* in_sizes, int n_in,
                              void* d_out, int out_size, void* d_ws, size_t ws_size,
                              hipStream_t stream) {
    const float* hs   = (const float*)d_in[0];
    const float* cosp = (const float*)d_in[1];
    const float* sinp = (const float*)d_in[2];
    const float* Wq   = (const float*)d_in[3];
    const float* Wk   = (const float*)d_in[4];
    const float* Wv   = (const float*)d_in[5];
    const float* Wo   = (const float*)d_in[6];
    const float* qw   = (const float*)d_in[7];
    const float* kw   = (const float*)d_in[8];
    float* out = (float*)d_out;

    char* ws = (char*)d_ws;
    size_t off = 0;
    auto carve = [&](size_t bytes) { char* p = ws + off; off += (bytes + 255) & ~(size_t)255; return p; };

    bf16* hsb  = (bf16*)carve((size_t)S_LEN * HIDDEN * 2);          // hidden bf16; reused as AO
    bf16* wqkv = (bf16*)carve((size_t)QKVW * HIDDEN * 2);           // fused [6144, 4096]
    bf16* wob  = (bf16*)carve((size_t)HIDDEN * NH * DH * 2);
    bf16* qkv  = (bf16*)carve((size_t)S_LEN * QKVW * 2);            // [S, 6144]
    bf16* vtb  = (bf16*)carve((size_t)NKV * DH * S_LEN * 2);

    // 1. casts
    cast_f32_bf16<<<(S_LEN * HIDDEN / 4 + 255) / 256, 256, 0, stream>>>(hs, (unsigned short*)hsb, S_LEN * HIDDEN / 4);
    cast_f32_bf16<<<(NH * DH * HIDDEN / 4 + 255) / 256, 256, 0, stream>>>(Wq, (unsigned short*)wqkv, NH * DH * HIDDEN / 4);
    cast_f32_bf16<<<(NKV * DH * HIDDEN / 4 + 255) / 256, 256, 0, stream>>>(Wk, (unsigned short*)(wqkv + (size_t)KOFF * HIDDEN), NKV * DH * HIDDEN / 4);
    cast_f32_bf16<<<(NKV * DH * HIDDEN / 4 + 255) / 256, 256, 0, stream>>>(Wv, (unsigned short*)(wqkv + (size_t)VOFF * HIDDEN), NKV * DH * HIDDEN / 4);
    cast_f32_bf16<<<(HIDDEN * NH * DH / 4 + 255) / 256, 256, 0, stream>>>(Wo, (unsigned short*)wob, HIDDEN * NH * DH / 4);

    // 2. fused QKV projection
    gemm_lds<bf16><<<dim3(QKVW / 128, S_LEN / 128), 256, 0, stream>>>(hsb, wqkv, qkv, S_LEN, QKVW, HIDDEN);

    // 3. rmsnorm + rope in place on Q and K slices
    norm_rope<<<S_LEN * NH / 4, 256, 0, stream>>>(qkv, qw, cosp, sinp, 5, QKVW, 0);
    norm_rope<<<S_LEN * NKV / 4, 256, 0, stream>>>(qkv, kw, cosp, sinp, 3, QKVW, KOFF);

    // 4. V transpose
    transpose_v<<<dim3(NKV * DH / 32, S_LEN / 64), 256, 0, stream>>>(qkv, vtb, QKVW, VOFF);

    // 5. flash attention -> AO (reuse hsb)
    bf16* aob = hsb;
    flash_attn<<<512, 256, 0, stream>>>(qkv, vtb, aob);

    // 6. output projection (fp32 out)
    gemm_lds<float><<<dim3(HIDDEN / 128, S_LEN / 128), 256, 0, stream>>>(aob, wob, out, S_LEN, HIDDEN, NH * DH);
}